// Round 2
// baseline (209.821 us; speedup 1.0000x reference)
//
#include <hip/hip_runtime.h>

#define NITER 3
#define LAMBDA 0.01f
#define EPS 1e-9f
#define LOG2PI 1.8378770664093453f

#define DIN 12
#define CIN 8
#define NI 216      // 27 * 8 input capsule-taps
#define NO 16       // output capsules
#define NE 16       // pose elements (4x4)
#define PPAD 20     // padded row stride for sP (floats) - keeps 16B align + bank spread
#define RPAD 17     // padded row stride for sRa (floats)

__global__ __launch_bounds__(512)
void caps_em_kernel(const float* __restrict__ pose,
                    const float* __restrict__ act,
                    const float* __restrict__ W,
                    const float* __restrict__ beta_v,
                    const float* __restrict__ beta_a,
                    float* __restrict__ out)
{
    __shared__ __align__(16) float sP[NI][PPAD];   // input poses, 16 floats each
    __shared__ float sRa[NI][RPAD];                // R*act weights (also holds e-step logits)
    __shared__ float sAct[NI];
    __shared__ float sPart[2][3][256];             // m1/m2/rs partials for 2 i-halves
    __shared__ __align__(16) float sPose[NO][NE];
    __shared__ __align__(16) float sIv[NO][NE];
    __shared__ float sCo[NO];

    const int t = threadIdx.x;
    const int b = blockIdx.x;            // 0..999 -> (od,oh,ow)
    const int od = b / 100;
    const int rem = b - od * 100;
    const int oh = rem / 10;
    const int ow = rem - oh * 10;

    const int e  = t & 15;               // pose element 0..15
    const int o  = (t >> 4) & 15;        // output capsule
    const int ih = t >> 8;               // i-half 0/1
    const int r  = e >> 2, c = e & 3;    // pose row/col

    // ---------- phase 0: stage P (216x16 f32) and activations ----------
    for (int u = t; u < NI * 4; u += 512) {
        int i = u >> 2, q = u & 3;
        int ci = i & 7, n = i >> 3;
        int kw = n % 3, n2 = n / 3;
        int kh = n2 % 3, kd = n2 / 3;
        const float4 v = *(const float4*)&pose[((((od + kd) * DIN + (oh + kh)) * DIN + (ow + kw)) * CIN + ci) * 16 + q * 4];
        *(float4*)&sP[i][q * 4] = v;
    }
    if (t < NI) {
        int i = t;
        int ci = i & 7, n = i >> 3;
        int kw = n % 3, n2 = n / 3;
        int kh = n2 % 3, kd = n2 / 3;
        sAct[t] = act[(((od + kd) * DIN + (oh + kh)) * DIN + (ow + kw)) * CIN + ci] + EPS;
    }
    __syncthreads();
    // init Ra = act/16 (uniform routing)
    for (int u = t; u < NI * NO; u += 512) {
        sRa[u >> 4][u & 15] = sAct[u >> 4] * (1.0f / 16.0f);
    }

    const float bv_o = beta_v[o];
    const float ba_o = beta_a[o];
    const int i0 = ih * 108;
    const int oe = t & 255;
    const float4* W4 = (const float4*)W;

    __syncthreads();

    for (int it = 0; it < NITER; ++it) {
        // ---------- m-step moment pass: thread (ih,o,e) accumulates over i ----------
        float m1 = 0.f, m2 = 0.f, rs = 0.f;
        for (int i = i0; i < i0 + 108; ++i) {
            const float4 w = W4[((i << 4) + o) * 4 + r];   // W[i][o][r][0..3]
            float v = w.x * sP[i][c] + w.y * sP[i][4 + c] + w.z * sP[i][8 + c] + w.w * sP[i][12 + c];
            float ra = sRa[i][o];
            m1 = fmaf(ra, v, m1);
            m2 = fmaf(ra * v, v, m2);
            rs += ra;
        }
        sPart[ih][0][oe] = m1;
        sPart[ih][1][oe] = m2;
        sPart[ih][2][oe] = rs;
        __syncthreads();   // B1
        m1 = sPart[0][0][oe] + sPart[1][0][oe];
        m2 = sPart[0][1][oe] + sPart[1][1][oe];
        rs = sPart[0][2][oe] + sPart[1][2][oe];

        const float inv_rs = 1.0f / rs;
        const float pe = m1 * inv_rs;                                  // pose[o][e]
        const float ve = fmaxf(m2 * inv_rs - pe * pe, 0.0f) + EPS;     // var + EPS (matches ref)
        const float lv = __logf(ve);

        // sum of log_var over the 16 pose elements (e spans lanes ^1^2^4^8)
        float SL = lv;
        SL += __shfl_xor(SL, 1);
        SL += __shfl_xor(SL, 2);
        SL += __shfl_xor(SL, 4);
        SL += __shfl_xor(SL, 8);

        const float cost  = rs * (16.0f * bv_o + 0.5f * SL);
        const float logit = LAMBDA * (ba_o - cost);

        if (it == NITER - 1) {
            // outputs: pose (1000*16*16) then act (1000*16)
            out[(b * NO + o) * NE + e] = pe;
            if (ih == 0 && e == 0) {
                out[256000 + b * NO + o] = 1.0f / (1.0f + __expf(-logit));  // exp(log_sigmoid)
            }
            return;
        }

        // stable log_sigmoid
        const float log_a = (logit >= 0.0f) ? -log1pf(__expf(-logit))
                                            : logit - log1pf(__expf(logit));
        const float iv = 1.0f / ve;
        if (ih == 0) {
            sPose[o][e] = pe;
            sIv[o][e]   = iv;
            if (e == 0) sCo[o] = log_a - 0.5f * SL - 8.0f * LOG2PI;
        }
        __syncthreads();   // B2

        // ---------- e-step pass: thread (ih,o,j) computes full Q[i][o] per i ----------
        {
            float pv[16], iv16[16], wv[16], pp[16];
            *(float4*)&pv[0]  = *(const float4*)&sPose[o][0];
            *(float4*)&pv[4]  = *(const float4*)&sPose[o][4];
            *(float4*)&pv[8]  = *(const float4*)&sPose[o][8];
            *(float4*)&pv[12] = *(const float4*)&sPose[o][12];
            *(float4*)&iv16[0]  = *(const float4*)&sIv[o][0];
            *(float4*)&iv16[4]  = *(const float4*)&sIv[o][4];
            *(float4*)&iv16[8]  = *(const float4*)&sIv[o][8];
            *(float4*)&iv16[12] = *(const float4*)&sIv[o][12];
            const float Co = sCo[o];
            for (int i = i0 + e; i < i0 + 108; i += 16) {
                *(float4*)&pp[0]  = *(const float4*)&sP[i][0];
                *(float4*)&pp[4]  = *(const float4*)&sP[i][4];
                *(float4*)&pp[8]  = *(const float4*)&sP[i][8];
                *(float4*)&pp[12] = *(const float4*)&sP[i][12];
                const float4* Wr = W4 + ((i << 4) + o) * 4;
                *(float4*)&wv[0]  = Wr[0];
                *(float4*)&wv[4]  = Wr[1];
                *(float4*)&wv[8]  = Wr[2];
                *(float4*)&wv[12] = Wr[3];
                float q = 0.f;
#pragma unroll
                for (int rr = 0; rr < 4; ++rr) {
#pragma unroll
                    for (int cc = 0; cc < 4; ++cc) {
                        float v = wv[rr * 4 + 0] * pp[0 * 4 + cc]
                                + wv[rr * 4 + 1] * pp[1 * 4 + cc]
                                + wv[rr * 4 + 2] * pp[2 * 4 + cc]
                                + wv[rr * 4 + 3] * pp[3 * 4 + cc];
                        float d = v - pv[rr * 4 + cc];
                        q = fmaf(d * d, iv16[rr * 4 + cc], q);
                    }
                }
                sRa[i][o] = Co - 0.5f * q;   // = log_a + lp  (pre-normalization logit)
            }
        }
        __syncthreads();   // B3

        // ---------- R update: softmax over o, times act ----------
        if (t < NI) {
            float l[16];
            float mx = -1e30f;
#pragma unroll
            for (int oo = 0; oo < 16; ++oo) { l[oo] = sRa[t][oo]; mx = fmaxf(mx, l[oo]); }
            float s = 0.f;
#pragma unroll
            for (int oo = 0; oo < 16; ++oo) { l[oo] = __expf(l[oo] - mx); s += l[oo]; }
            const float sc = sAct[t] / s;
#pragma unroll
            for (int oo = 0; oo < 16; ++oo) sRa[t][oo] = sc * l[oo];
        }
        __syncthreads();   // B4
    }
}

extern "C" void kernel_launch(void* const* d_in, const int* in_sizes, int n_in,
                              void* d_out, int out_size, void* d_ws, size_t ws_size,
                              hipStream_t stream) {
    const float* pose = (const float*)d_in[0];
    const float* actv = (const float*)d_in[1];
    const float* W    = (const float*)d_in[2];
    const float* bv   = (const float*)d_in[3];
    const float* ba   = (const float*)d_in[4];
    float* out = (float*)d_out;
    caps_em_kernel<<<dim3(1000), dim3(512), 0, stream>>>(pose, actv, W, bv, ba, out);
}

// Round 3
// 188.645 us; speedup vs baseline: 1.1123x; 1.1123x over previous
//
#include <hip/hip_runtime.h>

#define NITER 3
#define LAMBDA 0.01f
#define EPS 1e-9f
#define LOG2PI 1.8378770664093453f

#define DIN 12
#define CIN 8
#define NI 216      // 27 * 8 input capsule-taps
#define NO 16       // output capsules
#define PPAD 20     // sPT row stride (floats): 80B, 16B-aligned, breaks pow2 banks
#define RSTR 216    // sRaT row stride (floats): 864B rows, 16B-aligned

__global__ __launch_bounds__(256, 4)
void caps_em_kernel(const float* __restrict__ pose,
                    const float* __restrict__ act,
                    const float* __restrict__ W,
                    const float* __restrict__ beta_v,
                    const float* __restrict__ beta_a,
                    float* __restrict__ out)
{
    // sPT[i][c*4+k] = P[i][k*4+c]  (4x4 pose stored column-major -> vote col is 1 b128)
    __shared__ __align__(16) float sPT[NI][PPAD];
    __shared__ __align__(16) float sRaT[NO][RSTR];   // Ra transposed: [o][i]
    __shared__ __align__(16) float sAct[NI];
    __shared__ __align__(16) float sPoseT[NO][16];   // [o][c*4+r] (column-major)
    __shared__ __align__(16) float sIvT[NO][16];
    __shared__ float sCo[NO];

    const int t = threadIdx.x;
    const int b = blockIdx.x;            // 0..999 -> (od,oh,ow)
    const int od = b / 100;
    const int rem = b - od * 100;
    const int oh = rem / 10;
    const int ow = rem - oh * 10;

    const int e = t & 15;                // pose element (row-major id r*4+c)
    const int o = t >> 4;                // output capsule 0..15
    const int r = e >> 2, c = e & 3;

    // ---------- stage P (transposed) + act ----------
    for (int u = t; u < NI * 4; u += 256) {
        int i = u >> 2, q = u & 3;       // q = source row of the 4x4
        int ci = i & 7, n = i >> 3;
        int kw = n % 3, n2 = n / 3;
        int kh = n2 % 3, kd = n2 / 3;
        const float4 v = *(const float4*)&pose[((((od + kd) * DIN + (oh + kh)) * DIN + (ow + kw)) * CIN + ci) * 16 + q * 4];
        sPT[i][0 * 4 + q] = v.x;         // element (q, c=0..3) -> [c*4 + q]
        sPT[i][1 * 4 + q] = v.y;
        sPT[i][2 * 4 + q] = v.z;
        sPT[i][3 * 4 + q] = v.w;
    }
    if (t < NI) {
        int i = t;
        int ci = i & 7, n = i >> 3;
        int kw = n % 3, n2 = n / 3;
        int kh = n2 % 3, kd = n2 / 3;
        sAct[i] = act[(((od + kd) * DIN + (oh + kh)) * DIN + (ow + kw)) * CIN + ci] + EPS;
    }
    __syncthreads();
    // init Ra = act/16 (uniform routing), vectorized
    for (int u = t; u < (NI * NO) / 4; u += 256) {      // 864 quads
        int oo = u / 54, j = u - oo * 54;
        float4 a4 = *(const float4*)&sAct[j * 4];
        float4 w4 = make_float4(a4.x * (1.0f / 16.0f), a4.y * (1.0f / 16.0f),
                                a4.z * (1.0f / 16.0f), a4.w * (1.0f / 16.0f));
        *(float4*)&sRaT[oo][j * 4] = w4;
    }
    __syncthreads();

    const float bv_o = beta_v[o];
    const float ba_o = beta_a[o];
    const float4* W4 = (const float4*)W;          // W[i][o][r][0..3] at index i*64 + o*4 + r
    const float4* Wto = W4 + o * 4 + r;           // m-pass per-thread base, stride 64 per i

    for (int it = 0; it < NITER; ++it) {
        // ---------- m-step: thread (o,e) reduces over ALL 216 i in registers ----------
        float m1 = 0.f, m2 = 0.f, rs = 0.f;
        for (int i = 0; i < NI; i += 4) {
            const float4 ra4 = *(const float4*)&sRaT[o][i];   // broadcast across e-lanes
#pragma unroll
            for (int k = 0; k < 4; ++k) {
                const float4 w = Wto[(i + k) * 64];                    // W[i+k][o][r][:]
                const float4 p = *(const float4*)&sPT[i + k][c * 4];   // P[:, c]
                const float ra = (k == 0) ? ra4.x : (k == 1) ? ra4.y : (k == 2) ? ra4.z : ra4.w;
                float v = w.x * p.x;
                v = fmaf(w.y, p.y, v);
                v = fmaf(w.z, p.z, v);
                v = fmaf(w.w, p.w, v);               // vote[o][r][c]
                m1 = fmaf(ra, v, m1);
                m2 = fmaf(ra * v, v, m2);
                rs += ra;
            }
        }

        const float inv_rs = 1.0f / rs;
        const float pe = m1 * inv_rs;                                  // pose[o][e]
        const float ve = fmaxf(m2 * inv_rs - pe * pe, 0.0f) + EPS;     // var + EPS
        const float lv = __logf(ve);

        // sum log_var over 16 pose elements (e spans lane bits 0..3)
        float SL = lv;
        SL += __shfl_xor(SL, 1);
        SL += __shfl_xor(SL, 2);
        SL += __shfl_xor(SL, 4);
        SL += __shfl_xor(SL, 8);

        const float cost  = rs * (16.0f * bv_o + 0.5f * SL);
        const float logit = LAMBDA * (ba_o - cost);

        if (it == NITER - 1) {
            out[(b * NO + o) * 16 + e] = pe;                              // row-major id e
            if (e == 0) out[256000 + b * NO + o] = 1.0f / (1.0f + __expf(-logit));
            return;
        }

        // stable log_sigmoid
        const float log_a = (logit >= 0.0f) ? -log1pf(__expf(-logit))
                                            : logit - log1pf(__expf(logit));
        sPoseT[o][c * 4 + r] = pe;            // store column-major
        sIvT[o][c * 4 + r]   = 1.0f / ve;
        if (e == 0) sCo[o] = log_a - 0.5f * SL - 8.0f * LOG2PI;
        __syncthreads();   // B2: pose/iv/Co ready

        // ---------- e-step: lane e covers i = e, e+16, ...; full 4x4 vote per (i,o) ----------
        {
            float wv[16], pv[16], iv16[16];
            *(float4*)&pv[0]    = *(const float4*)&sPoseT[o][0];   // pv[cc*4+rr] = pose[rr][cc]
            *(float4*)&pv[4]    = *(const float4*)&sPoseT[o][4];
            *(float4*)&pv[8]    = *(const float4*)&sPoseT[o][8];
            *(float4*)&pv[12]   = *(const float4*)&sPoseT[o][12];
            *(float4*)&iv16[0]  = *(const float4*)&sIvT[o][0];
            *(float4*)&iv16[4]  = *(const float4*)&sIvT[o][4];
            *(float4*)&iv16[8]  = *(const float4*)&sIvT[o][8];
            *(float4*)&iv16[12] = *(const float4*)&sIvT[o][12];
            const float Co = sCo[o];
            for (int i = e; i < NI; i += 16) {
                const float4* Wr = W4 + i * 64 + o * 4;   // W[i][o][rr][:]
                *(float4*)&wv[0]  = Wr[0];
                *(float4*)&wv[4]  = Wr[1];
                *(float4*)&wv[8]  = Wr[2];
                *(float4*)&wv[12] = Wr[3];
                float q = 0.f;
#pragma unroll
                for (int cc = 0; cc < 4; ++cc) {
                    const float4 pt = *(const float4*)&sPT[i][cc * 4];   // P[k][cc], k=0..3
#pragma unroll
                    for (int rr = 0; rr < 4; ++rr) {
                        float v = wv[rr * 4 + 0] * pt.x;
                        v = fmaf(wv[rr * 4 + 1], pt.y, v);
                        v = fmaf(wv[rr * 4 + 2], pt.z, v);
                        v = fmaf(wv[rr * 4 + 3], pt.w, v);
                        const float d = v - pv[cc * 4 + rr];
                        q = fmaf(d * d, iv16[cc * 4 + rr], q);
                    }
                }
                sRaT[o][i] = Co - 0.5f * q;   // pre-normalization logit
            }
        }
        __syncthreads();   // B3: logits ready

        // ---------- R update: softmax over o, times act ----------
        if (t < NI) {
            float l[16];
            float mx = -1e30f;
#pragma unroll
            for (int oo = 0; oo < 16; ++oo) { l[oo] = sRaT[oo][t]; mx = fmaxf(mx, l[oo]); }
            float s = 0.f;
#pragma unroll
            for (int oo = 0; oo < 16; ++oo) { l[oo] = __expf(l[oo] - mx); s += l[oo]; }
            const float sc = sAct[t] / s;
#pragma unroll
            for (int oo = 0; oo < 16; ++oo) sRaT[oo][t] = sc * l[oo];
        }
        __syncthreads();   // B4: Ra ready
    }
}

extern "C" void kernel_launch(void* const* d_in, const int* in_sizes, int n_in,
                              void* d_out, int out_size, void* d_ws, size_t ws_size,
                              hipStream_t stream) {
    const float* pose = (const float*)d_in[0];
    const float* actv = (const float*)d_in[1];
    const float* W    = (const float*)d_in[2];
    const float* bv   = (const float*)d_in[3];
    const float* ba   = (const float*)d_in[4];
    float* out = (float*)d_out;
    caps_em_kernel<<<dim3(1000), dim3(256), 0, stream>>>(pose, actv, W, bv, ba, out);
}